// Round 7
// baseline (82.952 us; speedup 1.0000x reference)
//
#include <hip/hip_runtime.h>

#define NF 40
#define ED 128
#define NB 1024
#define NIX 780
#define NC 20               // field chunks of 2
#define CROSS 190           // NC*(NC-1)/2
#define XROW (NF * ED)      // 5120
#define KROW (NIX * ED)     // 99840
#define XB_BYTES (NB * NF * ED * 2)   // 13,107,200
#define KB_BYTES (NIX * ED * ED * 2)  // 25,559,040
#define WS_NEED (XB_BYTES + KB_BYTES)

typedef __attribute__((ext_vector_type(8))) short bf16x8;
typedef __attribute__((ext_vector_type(4))) float f32x4;
typedef __attribute__((ext_vector_type(4))) unsigned short ushx4;
typedef __attribute__((ext_vector_type(8))) unsigned short ushx8;

__device__ __forceinline__ unsigned short f2bf(float x) {
  unsigned int u = __float_as_uint(x);
  u = (u + 0x7FFFu + ((u >> 16) & 1u)) >> 16;
  return (unsigned short)u;
}
__device__ __forceinline__ float bf2f(unsigned short h) {
  return __uint_as_float(((unsigned int)h) << 16);
}

#define GLOAD16(gsrc, ldst)                                                    \
  __builtin_amdgcn_global_load_lds(                                            \
      (const __attribute__((address_space(1))) void*)(gsrc),                   \
      (__attribute__((address_space(3))) void*)(ldst), 16, 0, 0)

// ---- fused prepass: x fp32->bf16 (blocks 0..2559), K [e][n][d]->[n][e][d] bf16 ----
__global__ void cvt_fused(const float* __restrict__ x, const float* __restrict__ kr,
                          unsigned short* __restrict__ xb, unsigned short* __restrict__ kb) {
  const int blk = blockIdx.x;
  if (blk < 2560) {
    const size_t g = ((size_t)blk * 256 + threadIdx.x) * 8;
    float4 a = *reinterpret_cast<const float4*>(x + g);
    float4 b = *reinterpret_cast<const float4*>(x + g + 4);
    ushx8 h;
    h[0] = f2bf(a.x); h[1] = f2bf(a.y); h[2] = f2bf(a.z); h[3] = f2bf(a.w);
    h[4] = f2bf(b.x); h[5] = f2bf(b.y); h[6] = f2bf(b.z); h[7] = f2bf(b.w);
    *reinterpret_cast<ushx8*>(xb + g) = h;
  } else {
    const size_t g = ((size_t)(blk - 2560) * 256 + threadIdx.x) * 4;
    const int d = (int)(g & 127);
    const size_t t = g >> 7;
    const int e = (int)(t & 127);
    const int n = (int)(t >> 7);
    float4 v = *reinterpret_cast<const float4*>(kr + ((size_t)e * NIX + n) * ED + d);
    ushx4 h;
    h[0] = f2bf(v.x); h[1] = f2bf(v.y); h[2] = f2bf(v.z); h[3] = f2bf(v.w);
    *reinterpret_cast<ushx4*>(kb + g) = h;
  }
}

__device__ __forceinline__ int nix_of(int i, int j) {  // triangular pair index
  return i * (2 * NF - i - 1) / 2 + (j - i - 1);
}

// ---- main: 2x2 pair-chunked blocks, e-split K in regs (4 pairs), 32-row b-tiles ----
__launch_bounds__(256, 2)
__global__ void opn_ws(const unsigned short* __restrict__ xb,
                       const unsigned short* __restrict__ kb,
                       float* __restrict__ out) {
  // 64 KB: K staging (two 32 KB Ks per round); tile loop reuses first 32 KB
  // as 4 field planes of 8 KB each.
  __shared__ unsigned short S[32768];
  __shared__ float scratch[4][4][32];  // [warp][pair][b]

  const int tid = threadIdx.x;
  const int lane = tid & 63;
  const int w = tid >> 6;
  const int lm = lane & 15;
  const int lq = lane >> 4;
  const int col8 = lm * 8;

  // ---- decode block -> field chunk-pair ----
  const int bid = blockIdx.x;
  int fP0, fP1, fQ0, fQ1, np, nq;
  if (bid < CROSS) {
    int ca = 0, base = 0;
    while (base + (NC - 1 - ca) <= bid) { base += NC - 1 - ca; ++ca; }
    const int cb = ca + 1 + (bid - base);
    fP0 = 2 * ca; fP1 = fP0 + 1; fQ0 = 2 * cb; fQ1 = fQ0 + 1;
    np = 2; nq = 2;
  } else {
    const int c = bid - CROSS;
    fP0 = 2 * c; fP1 = fP0; fQ0 = fP0 + 1; fQ1 = fQ0;
    np = 1; nq = 1;
  }
  const int n00 = nix_of(fP0, fQ0);
  const int n01 = (nq == 2) ? n00 + 1 : n00;
  const int n10 = (np == 2) ? nix_of(fP1, fQ0) : n00;

  // ---- K staging round A: n00 -> S[0..], n01 -> S[16384..] ----
  {
    const unsigned short* kA = kb + (size_t)n00 * (ED * ED);
    const unsigned short* kBp = kb + (size_t)n01 * (ED * ED);
    #pragma unroll
    for (int j = 0; j < 8; ++j) {
      const int chunk = j * 4 + w;         // 0..31, 1KB
      const int r = chunk * 4 + lq;        // 0..127
      const int c = col8 ^ ((r & 7) << 3);
      GLOAD16(kA + r * ED + c, S + chunk * 512);
      GLOAD16(kBp + r * ED + c, S + 16384 + chunk * 512);
    }
  }
  __syncthreads();

  // hoist e-quarter fragments: A[m=e][k=d], e = w*32 + f*16 + lm
  bf16x8 kfr00[4][2], kfr01[4][2], kfr10[4][2], kfr11[4][2];
  #pragma unroll
  for (int kk = 0; kk < 4; ++kk)
    #pragma unroll
    for (int f = 0; f < 2; ++f) {
      const int r = w * 32 + f * 16 + lm;
      const int off = r * ED + ((kk * 32 + lq * 8) ^ ((r & 7) << 3));
      kfr00[kk][f] = *reinterpret_cast<const bf16x8*>(&S[off]);
      kfr01[kk][f] = *reinterpret_cast<const bf16x8*>(&S[16384 + off]);
    }
  #pragma unroll
  for (int kk = 0; kk < 4; ++kk)
    #pragma unroll
    for (int f = 0; f < 2; ++f) {
      asm volatile("" : "+v"(kfr00[kk][f]));
      asm volatile("" : "+v"(kfr01[kk][f]));
    }
  __syncthreads();

  // ---- K staging round B: n10, n11 ----
  {
    const unsigned short* kA = kb + (size_t)n10 * (ED * ED);
    const unsigned short* kBp = kb + (size_t)(n10 + (nq == 2 ? 1 : 0)) * (ED * ED);
    #pragma unroll
    for (int j = 0; j < 8; ++j) {
      const int chunk = j * 4 + w;
      const int r = chunk * 4 + lq;
      const int c = col8 ^ ((r & 7) << 3);
      GLOAD16(kA + r * ED + c, S + chunk * 512);
      GLOAD16(kBp + r * ED + c, S + 16384 + chunk * 512);
    }
  }
  __syncthreads();
  #pragma unroll
  for (int kk = 0; kk < 4; ++kk)
    #pragma unroll
    for (int f = 0; f < 2; ++f) {
      const int r = w * 32 + f * 16 + lm;
      const int off = r * ED + ((kk * 32 + lq * 8) ^ ((r & 7) << 3));
      kfr10[kk][f] = *reinterpret_cast<const bf16x8*>(&S[off]);
      kfr11[kk][f] = *reinterpret_cast<const bf16x8*>(&S[16384 + off]);
    }
  #pragma unroll
  for (int kk = 0; kk < 4; ++kk)
    #pragma unroll
    for (int f = 0; f < 2; ++f) {
      asm volatile("" : "+v"(kfr10[kk][f]));
      asm volatile("" : "+v"(kfr11[kk][f]));
    }
  __syncthreads();

  unsigned short* PlP0 = S;             // 4 planes x 8 KB (4096 shorts)
  unsigned short* PlP1 = S + 4096;
  unsigned short* PlQ0 = S + 8192;
  unsigned short* PlQ1 = S + 12288;

  const int b0base = blockIdx.y * 256;

  // per-pair compute: T = K_e-quarter @ P^T, then partial dot with Q
  auto pair_compute = [&](const bf16x8 (&kf)[4][2], const bf16x8 (&pf)[2][4],
                          const unsigned short* Qp, int pidx) {
    f32x4 acc[2][2];
    #pragma unroll
    for (int f = 0; f < 2; ++f)
      #pragma unroll
      for (int nt = 0; nt < 2; ++nt)
        acc[f][nt] = (f32x4){0.f, 0.f, 0.f, 0.f};
    __builtin_amdgcn_s_setprio(1);
    #pragma unroll
    for (int kk = 0; kk < 4; ++kk)
      #pragma unroll
      for (int nt = 0; nt < 2; ++nt)
        #pragma unroll
        for (int f = 0; f < 2; ++f)
          acc[f][nt] = __builtin_amdgcn_mfma_f32_16x16x32_bf16(
              kf[kk][f], pf[nt][kk], acc[f][nt], 0, 0, 0);
    __builtin_amdgcn_s_setprio(0);
    // lane holds T[e = w*32 + f*16 + lq*4 + r][b = nt*16 + lm]
    #pragma unroll
    for (int nt = 0; nt < 2; ++nt) {
      const int qrow = nt * 16 + lm;
      float t0 = 0.f, t1 = 0.f, t2 = 0.f, t3 = 0.f;
      #pragma unroll
      for (int f = 0; f < 2; ++f) {
        const int c = (w * 32 + f * 16 + lq * 4) ^ ((qrow & 7) << 3);
        ushx4 q4 = *reinterpret_cast<const ushx4*>(&Qp[qrow * ED + c]);
        t0 = fmaf(acc[f][nt][0], bf2f(q4[0]), t0);
        t1 = fmaf(acc[f][nt][1], bf2f(q4[1]), t1);
        t2 = fmaf(acc[f][nt][2], bf2f(q4[2]), t2);
        t3 = fmaf(acc[f][nt][3], bf2f(q4[3]), t3);
      }
      float sv = (t0 + t1) + (t2 + t3);
      sv += __shfl_xor(sv, 16);
      sv += __shfl_xor(sv, 32);
      if (lq == 0) scratch[w][pidx][nt * 16 + lm] = sv;
    }
  };

  #pragma unroll 1
  for (int t = 0; t < 8; ++t) {
    const int b0 = b0base + t * 32;

    // ---- stage 4 field planes (8 loads/thread, 32 KB) ----
    #pragma unroll
    for (int pl = 0; pl < 4; ++pl) {
      const int fld = (pl == 0) ? fP0 : (pl == 1) ? fP1 : (pl == 2) ? fQ0 : fQ1;
      #pragma unroll
      for (int j = 0; j < 2; ++j) {
        const int chunk = j * 4 + w;       // 0..7
        const int r = chunk * 4 + lq;      // 0..31
        const int c = col8 ^ ((r & 7) << 3);
        GLOAD16(xb + (size_t)(b0 + r) * XROW + (size_t)fld * ED + c,
                S + pl * 4096 + chunk * 512);
      }
    }
    __syncthreads();

    // ---- compute 4 (or 1) pairs; P-fragments shared across the Q axis ----
    {
      bf16x8 pf0[2][4];
      #pragma unroll
      for (int nt = 0; nt < 2; ++nt)
        #pragma unroll
        for (int kk = 0; kk < 4; ++kk) {
          const int pb = nt * 16 + lm;
          pf0[nt][kk] = *reinterpret_cast<const bf16x8*>(
              &PlP0[pb * ED + ((kk * 32 + lq * 8) ^ ((pb & 7) << 3))]);
        }
      pair_compute(kfr00, pf0, PlQ0, 0);
      if (nq == 2) pair_compute(kfr01, pf0, PlQ1, 1);
    }
    if (np == 2) {
      bf16x8 pf1[2][4];
      #pragma unroll
      for (int nt = 0; nt < 2; ++nt)
        #pragma unroll
        for (int kk = 0; kk < 4; ++kk) {
          const int pb = nt * 16 + lm;
          pf1[nt][kk] = *reinterpret_cast<const bf16x8*>(
              &PlP1[pb * ED + ((kk * 32 + lq * 8) ^ ((pb & 7) << 3))]);
        }
      pair_compute(kfr10, pf1, PlQ0, 2);
      pair_compute(kfr11, pf1, PlQ1, 3);
    }
    __syncthreads();  // scratch ready; all plane reads done

    // ---- cross-warp reduce + store ----
    if (bid < CROSS) {
      if (tid < 128) {
        const int pair = tid >> 5;         // 0..3
        const int b = tid & 31;
        const float v = (scratch[0][pair][b] + scratch[1][pair][b]) +
                        (scratch[2][pair][b] + scratch[3][pair][b]);
        const int nsel = ((pair & 2) ? n10 : n00) + (pair & 1);
        out[(size_t)(b0 + b) * NIX + nsel] = v;
      }
    } else {
      if (tid < 32) {
        const int b = tid;
        const float v = (scratch[0][0][b] + scratch[1][0][b]) +
                        (scratch[2][0][b] + scratch[3][0][b]);
        out[(size_t)(b0 + b) * NIX + n00] = v;
      }
    }
  }
}

// ---------------- fallback (proven Round-1 kernel, used when ws too small) ----------------
__device__ __forceinline__ int swz_fb(int row, int col) {
  return row * 128 + (col ^ ((row & 7) << 3));
}

__launch_bounds__(256, 2)
__global__ void opn_fb(const float* __restrict__ x,
                       const float* __restrict__ kern,
                       float* __restrict__ out) {
  __shared__ unsigned short Klds[128 * 128];
  __shared__ unsigned short Plds[64 * 128];
  __shared__ unsigned short Qlds[64 * 132];

  const int n = blockIdx.x;
  const int tid = threadIdx.x;
  const int lane = tid & 63;
  const int w = tid >> 6;
  const int lm = lane & 15;
  const int lq = lane >> 4;

  int fi = 0, base = 0;
  while (base + (NF - 1 - fi) <= n) { base += NF - 1 - fi; ++fi; }
  const int fj = fi + 1 + (n - base);

  {
    const int r8 = tid >> 5;
    const int d0 = (tid & 31) * 4;
    const float* kbp = kern + (size_t)n * ED + d0;
    #pragma unroll
    for (int p = 0; p < 16; ++p) {
      int e = p * 8 + r8;
      float4 v = *reinterpret_cast<const float4*>(kbp + (size_t)e * KROW);
      ushx4 h;
      h[0] = f2bf(v.x); h[1] = f2bf(v.y); h[2] = f2bf(v.z); h[3] = f2bf(v.w);
      *reinterpret_cast<ushx4*>(&Klds[swz_fb(e, d0)]) = h;
    }
  }
  __syncthreads();

  bf16x8 bfr[4][8];
  #pragma unroll
  for (int kk = 0; kk < 4; ++kk)
    #pragma unroll
    for (int f = 0; f < 8; ++f)
      bfr[kk][f] = *reinterpret_cast<const bf16x8*>(
          &Klds[swz_fb(f * 16 + lm, kk * 32 + lq * 8)]);

  const int r8 = tid >> 5;
  const int c4 = (tid & 31) * 4;

  for (int t = 0; t < 8; ++t) {
    const int b0 = blockIdx.y * 512 + t * 64;
    __syncthreads();
    #pragma unroll
    for (int p = 0; p < 8; ++p) {
      int r = p * 8 + r8;
      const float* xbp = x + (size_t)(b0 + r) * XROW + c4;
      float4 vp = *reinterpret_cast<const float4*>(xbp + fi * ED);
      ushx4 hp;
      hp[0] = f2bf(vp.x); hp[1] = f2bf(vp.y); hp[2] = f2bf(vp.z); hp[3] = f2bf(vp.w);
      *reinterpret_cast<ushx4*>(&Plds[swz_fb(r, c4)]) = hp;
      float4 vq = *reinterpret_cast<const float4*>(xbp + fj * ED);
      ushx4 hq;
      hq[0] = f2bf(vq.x); hq[1] = f2bf(vq.y); hq[2] = f2bf(vq.z); hq[3] = f2bf(vq.w);
      *reinterpret_cast<ushx4*>(&Qlds[r * 132 + c4]) = hq;
    }
    __syncthreads();

    f32x4 acc[8];
    #pragma unroll
    for (int f = 0; f < 8; ++f) acc[f] = (f32x4){0.f, 0.f, 0.f, 0.f};
    #pragma unroll
    for (int kk = 0; kk < 4; ++kk) {
      bf16x8 a = *reinterpret_cast<const bf16x8*>(
          &Plds[swz_fb(w * 16 + lm, kk * 32 + lq * 8)]);
      #pragma unroll
      for (int f = 0; f < 8; ++f)
        acc[f] = __builtin_amdgcn_mfma_f32_16x16x32_bf16(a, bfr[kk][f], acc[f], 0, 0, 0);
    }

    #pragma unroll
    for (int r = 0; r < 4; ++r) {
      const int bl = w * 16 + lq * 4 + r;
      float s = 0.f;
      #pragma unroll
      for (int f = 0; f < 8; ++f)
        s = fmaf(acc[f][r], bf2f(Qlds[bl * 132 + f * 16 + lm]), s);
      s += __shfl_xor(s, 1);
      s += __shfl_xor(s, 2);
      s += __shfl_xor(s, 4);
      s += __shfl_xor(s, 8);
      if (lm == 0) out[(size_t)(b0 + bl) * NIX + n] = s;
    }
  }
}

extern "C" void kernel_launch(void* const* d_in, const int* in_sizes, int n_in,
                              void* d_out, int out_size, void* d_ws, size_t ws_size,
                              hipStream_t stream) {
  const float* x = (const float*)d_in[0];
  const float* kern = (const float*)d_in[1];
  float* out = (float*)d_out;
  (void)in_sizes; (void)n_in; (void)out_size;

  if (ws_size >= (size_t)WS_NEED) {
    unsigned short* xb = (unsigned short*)d_ws;
    unsigned short* kbuf = (unsigned short*)((char*)d_ws + XB_BYTES);
    cvt_fused<<<15040, 256, 0, stream>>>(x, kern, xb, kbuf);
    dim3 grid(CROSS + NC, 4, 1);   // 210 x 4 = 840 blocks
    opn_ws<<<grid, 256, 0, stream>>>(xb, kbuf, out);
  } else {
    dim3 grid(NIX, 2, 1);
    opn_fb<<<grid, 256, 0, stream>>>(x, kern, out);
  }
}

// Round 8
// 70.297 us; speedup vs baseline: 1.1800x; 1.1800x over previous
//
#include <hip/hip_runtime.h>

#define NF 40
#define ED 128
#define NB 1024
#define NIX 780
#define XROW (NF * ED)      // 5120
#define KROW (NIX * ED)     // 99840
#define XB_BYTES (NB * NF * ED * 2)   // 13,107,200
#define KB_BYTES (NIX * ED * ED * 2)  // 25,559,040
#define WS_NEED (XB_BYTES + KB_BYTES)

typedef __attribute__((ext_vector_type(8))) short bf16x8;
typedef __attribute__((ext_vector_type(4))) float f32x4;
typedef __attribute__((ext_vector_type(4))) unsigned short ushx4;
typedef __attribute__((ext_vector_type(8))) unsigned short ushx8;

__device__ __forceinline__ unsigned short f2bf(float x) {
  unsigned int u = __float_as_uint(x);
  u = (u + 0x7FFFu + ((u >> 16) & 1u)) >> 16;
  return (unsigned short)u;
}
__device__ __forceinline__ float bf2f(unsigned short h) {
  return __uint_as_float(((unsigned int)h) << 16);
}

#define GLOAD16(gsrc, ldst)                                                    \
  __builtin_amdgcn_global_load_lds(                                            \
      (const __attribute__((address_space(1))) void*)(gsrc),                   \
      (__attribute__((address_space(3))) void*)(ldst), 16, 0, 0)

// ---- fused prepass: x fp32->bf16 (blocks 0..2559), K [e][n][d]->[n][e][d] bf16 ----
__global__ void cvt_fused(const float* __restrict__ x, const float* __restrict__ kr,
                          unsigned short* __restrict__ xb, unsigned short* __restrict__ kb) {
  const int blk = blockIdx.x;
  if (blk < 2560) {
    const size_t g = ((size_t)blk * 256 + threadIdx.x) * 8;
    float4 a = *reinterpret_cast<const float4*>(x + g);
    float4 b = *reinterpret_cast<const float4*>(x + g + 4);
    ushx8 h;
    h[0] = f2bf(a.x); h[1] = f2bf(a.y); h[2] = f2bf(a.z); h[3] = f2bf(a.w);
    h[4] = f2bf(b.x); h[5] = f2bf(b.y); h[6] = f2bf(b.z); h[7] = f2bf(b.w);
    *reinterpret_cast<ushx8*>(xb + g) = h;
  } else {
    const size_t g = ((size_t)(blk - 2560) * 256 + threadIdx.x) * 4;
    const int d = (int)(g & 127);
    const size_t t = g >> 7;
    const int e = (int)(t & 127);
    const int n = (int)(t >> 7);
    float4 v = *reinterpret_cast<const float4*>(kr + ((size_t)e * NIX + n) * ED + d);
    ushx4 h;
    h[0] = f2bf(v.x); h[1] = f2bf(v.y); h[2] = f2bf(v.z); h[3] = f2bf(v.w);
    *reinterpret_cast<ushx4*>(kb + g) = h;
  }
}

// ---- main kernel: e-split warps, 32-row b-tiles, XCD-locked b-range ----
// Block mapping: XCD = bid%8 (hardware round-robin). y=(bid%8)>>1 fixes the
// 256-row b-slice per XCD, so each XCD's x working set is 256*40*128*2 =
// 3.25 MB < 4 MB L2 -> x re-reads served by per-XCD L2, not L3.
__launch_bounds__(256, 4)
__global__ void opn_ws(const unsigned short* __restrict__ xb,
                       const unsigned short* __restrict__ kb,
                       float* __restrict__ out) {
  // 32 KB: K staging first; after hoist reused as P[0..4095] + Q[4096..8191]
  __shared__ unsigned short S[16384];
  __shared__ float scratch[4][32];   // per-warp partial dots

  const int bid = blockIdx.x;
  const int g8 = bid & 7;
  const int n = ((bid >> 3) << 1) + (g8 & 1);   // pair index, 0..779
  const int b0base = (g8 >> 1) * 256;           // b-slice locked to XCD pair

  const int tid = threadIdx.x;
  const int lane = tid & 63;
  const int w = tid >> 6;
  const int lm = lane & 15;
  const int lq = lane >> 4;
  const int col8 = lm * 8;

  // pair (fi, fj)
  int fi = 0, base = 0;
  while (base + (NF - 1 - fi) <= n) { base += NF - 1 - fi; ++fi; }
  const int fj = fi + 1 + (n - base);

  // ---- stage K (32 KB) via global_load_lds, pre-swizzled source ----
  {
    const unsigned short* ks = kb + (size_t)n * (ED * ED);
    #pragma unroll
    for (int j = 0; j < 8; ++j) {
      const int chunk = j * 4 + w;           // 0..31, 1KB each
      const int r = chunk * 4 + lq;          // 0..127
      const int c = col8 ^ ((r & 7) << 3);
      GLOAD16(ks + r * ED + c, S + chunk * 512);
    }
  }
  __syncthreads();

  // ---- hoist this warp's e-quarter: A[m=e][k=d], e = w*32 + f*16 + lm ----
  bf16x8 afr[4][2];
  #pragma unroll
  for (int kk = 0; kk < 4; ++kk)
    #pragma unroll
    for (int f = 0; f < 2; ++f) {
      const int r = w * 32 + f * 16 + lm;
      afr[kk][f] = *reinterpret_cast<const bf16x8*>(
          &S[r * ED + ((kk * 32 + lq * 8) ^ ((r & 7) << 3))]);
    }
  #pragma unroll
  for (int kk = 0; kk < 4; ++kk)
    #pragma unroll
    for (int f = 0; f < 2; ++f)
      asm volatile("" : "+v"(afr[kk][f]));   // pin: forbid remat from LDS
  __syncthreads();                            // all warps done reading K area

  unsigned short* Plds = S;                   // 8 KB
  unsigned short* Qlds = S + 4096;            // 8 KB

  #pragma unroll 1
  for (int t = 0; t < 8; ++t) {
    const int b0 = b0base + t * 32;

    // ---- stage P,Q (4 loads/thread, 16 KB) ----
    #pragma unroll
    for (int j = 0; j < 2; ++j) {
      const int chunk = j * 4 + w;           // 0..7
      const int r = chunk * 4 + lq;          // 0..31
      const int c = col8 ^ ((r & 7) << 3);
      const size_t xoff = (size_t)(b0 + r) * XROW + c;
      GLOAD16(xb + xoff + (size_t)fi * ED, Plds + chunk * 512);
      GLOAD16(xb + xoff + (size_t)fj * ED, Qlds + chunk * 512);
    }
    __syncthreads();   // full drain: tile staged

    // ---- T-quarter = K_w @ P^T : D[m=e][col=b], nt = b-subtile ----
    f32x4 acc[2][2];
    #pragma unroll
    for (int f = 0; f < 2; ++f)
      #pragma unroll
      for (int nt = 0; nt < 2; ++nt)
        acc[f][nt] = (f32x4){0.f, 0.f, 0.f, 0.f};

    __builtin_amdgcn_s_setprio(1);
    #pragma unroll
    for (int kk = 0; kk < 4; ++kk) {
      #pragma unroll
      for (int nt = 0; nt < 2; ++nt) {
        const int pb = nt * 16 + lm;
        bf16x8 pfr = *reinterpret_cast<const bf16x8*>(
            &Plds[pb * ED + ((kk * 32 + lq * 8) ^ ((pb & 7) << 3))]);
        #pragma unroll
        for (int f = 0; f < 2; ++f)
          acc[f][nt] = __builtin_amdgcn_mfma_f32_16x16x32_bf16(afr[kk][f], pfr, acc[f][nt], 0, 0, 0);
      }
    }
    __builtin_amdgcn_s_setprio(0);

    // ---- partial dot over this warp's e-quarter ----
    // lane holds T[e = w*32 + f*16 + lq*4 + r][b = nt*16 + lm]
    float s[2];
    #pragma unroll
    for (int nt = 0; nt < 2; ++nt) {
      const int qrow = nt * 16 + lm;
      float t0 = 0.f, t1 = 0.f, t2 = 0.f, t3 = 0.f;
      #pragma unroll
      for (int f = 0; f < 2; ++f) {
        const int c = (w * 32 + f * 16 + lq * 4) ^ ((qrow & 7) << 3);
        ushx4 q4 = *reinterpret_cast<const ushx4*>(&Qlds[qrow * ED + c]);
        t0 = fmaf(acc[f][nt][0], bf2f(q4[0]), t0);
        t1 = fmaf(acc[f][nt][1], bf2f(q4[1]), t1);
        t2 = fmaf(acc[f][nt][2], bf2f(q4[2]), t2);
        t3 = fmaf(acc[f][nt][3], bf2f(q4[3]), t3);
      }
      float sv = (t0 + t1) + (t2 + t3);
      sv += __shfl_xor(sv, 16);   // sum over lq groups (e-sub-quarters)
      sv += __shfl_xor(sv, 32);
      s[nt] = sv;
    }
    if (lq == 0) {                // lanes 0..15 of each warp
      scratch[w][lm] = s[0];
      scratch[w][16 + lm] = s[1];
    }
    __syncthreads();              // scratch ready; all tile reads done

    if (tid < 32) {               // cross-warp reduce + store
      const int b = tid;
      float r = (scratch[0][b] + scratch[1][b]) + (scratch[2][b] + scratch[3][b]);
      out[(size_t)(b0 + b) * NIX + n] = r;
    }
    // next stage writes Plds/Qlds, whose reads completed before the barrier;
    // the next scratch write is separated from this read by the next barrier.
  }
}

// ---------------- fallback (proven Round-1 kernel, used when ws too small) ----------------
__device__ __forceinline__ int swz_fb(int row, int col) {
  return row * 128 + (col ^ ((row & 7) << 3));
}

__launch_bounds__(256, 2)
__global__ void opn_fb(const float* __restrict__ x,
                       const float* __restrict__ kern,
                       float* __restrict__ out) {
  __shared__ unsigned short Klds[128 * 128];
  __shared__ unsigned short Plds[64 * 128];
  __shared__ unsigned short Qlds[64 * 132];

  const int n = blockIdx.x;
  const int tid = threadIdx.x;
  const int lane = tid & 63;
  const int w = tid >> 6;
  const int lm = lane & 15;
  const int lq = lane >> 4;

  int fi = 0, base = 0;
  while (base + (NF - 1 - fi) <= n) { base += NF - 1 - fi; ++fi; }
  const int fj = fi + 1 + (n - base);

  {
    const int r8 = tid >> 5;
    const int d0 = (tid & 31) * 4;
    const float* kbp = kern + (size_t)n * ED + d0;
    #pragma unroll
    for (int p = 0; p < 16; ++p) {
      int e = p * 8 + r8;
      float4 v = *reinterpret_cast<const float4*>(kbp + (size_t)e * KROW);
      ushx4 h;
      h[0] = f2bf(v.x); h[1] = f2bf(v.y); h[2] = f2bf(v.z); h[3] = f2bf(v.w);
      *reinterpret_cast<ushx4*>(&Klds[swz_fb(e, d0)]) = h;
    }
  }
  __syncthreads();

  bf16x8 bfr[4][8];
  #pragma unroll
  for (int kk = 0; kk < 4; ++kk)
    #pragma unroll
    for (int f = 0; f < 8; ++f)
      bfr[kk][f] = *reinterpret_cast<const bf16x8*>(
          &Klds[swz_fb(f * 16 + lm, kk * 32 + lq * 8)]);

  const int r8 = tid >> 5;
  const int c4 = (tid & 31) * 4;

  for (int t = 0; t < 8; ++t) {
    const int b0 = blockIdx.y * 512 + t * 64;
    __syncthreads();
    #pragma unroll
    for (int p = 0; p < 8; ++p) {
      int r = p * 8 + r8;
      const float* xbp = x + (size_t)(b0 + r) * XROW + c4;
      float4 vp = *reinterpret_cast<const float4*>(xbp + fi * ED);
      ushx4 hp;
      hp[0] = f2bf(vp.x); hp[1] = f2bf(vp.y); hp[2] = f2bf(vp.z); hp[3] = f2bf(vp.w);
      *reinterpret_cast<ushx4*>(&Plds[swz_fb(r, c4)]) = hp;
      float4 vq = *reinterpret_cast<const float4*>(xbp + fj * ED);
      ushx4 hq;
      hq[0] = f2bf(vq.x); hq[1] = f2bf(vq.y); hq[2] = f2bf(vq.z); hq[3] = f2bf(vq.w);
      *reinterpret_cast<ushx4*>(&Qlds[r * 132 + c4]) = hq;
    }
    __syncthreads();

    f32x4 acc[8];
    #pragma unroll
    for (int f = 0; f < 8; ++f) acc[f] = (f32x4){0.f, 0.f, 0.f, 0.f};
    #pragma unroll
    for (int kk = 0; kk < 4; ++kk) {
      bf16x8 a = *reinterpret_cast<const bf16x8*>(
          &Plds[swz_fb(w * 16 + lm, kk * 32 + lq * 8)]);
      #pragma unroll
      for (int f = 0; f < 8; ++f)
        acc[f] = __builtin_amdgcn_mfma_f32_16x16x32_bf16(a, bfr[kk][f], acc[f], 0, 0, 0);
    }

    #pragma unroll
    for (int r = 0; r < 4; ++r) {
      const int bl = w * 16 + lq * 4 + r;
      float s = 0.f;
      #pragma unroll
      for (int f = 0; f < 8; ++f)
        s = fmaf(acc[f][r], bf2f(Qlds[bl * 132 + f * 16 + lm]), s);
      s += __shfl_xor(s, 1);
      s += __shfl_xor(s, 2);
      s += __shfl_xor(s, 4);
      s += __shfl_xor(s, 8);
      if (lm == 0) out[(size_t)(b0 + bl) * NIX + n] = s;
    }
  }
}

extern "C" void kernel_launch(void* const* d_in, const int* in_sizes, int n_in,
                              void* d_out, int out_size, void* d_ws, size_t ws_size,
                              hipStream_t stream) {
  const float* x = (const float*)d_in[0];
  const float* kern = (const float*)d_in[1];
  float* out = (float*)d_out;
  (void)in_sizes; (void)n_in; (void)out_size;

  if (ws_size >= (size_t)WS_NEED) {
    unsigned short* xb = (unsigned short*)d_ws;
    unsigned short* kbuf = (unsigned short*)((char*)d_ws + XB_BYTES);
    cvt_fused<<<15040, 256, 0, stream>>>(x, kern, xb, kbuf);
    opn_ws<<<3120, 256, 0, stream>>>(xb, kbuf, out);  // 390*8: bid%8 locks b-slice to XCD
  } else {
    dim3 grid(NIX, 2, 1);
    opn_fb<<<grid, 256, 0, stream>>>(x, kern, out);
  }
}

// Round 9
// 70.106 us; speedup vs baseline: 1.1832x; 1.0027x over previous
//
#include <hip/hip_runtime.h>

#define NF 40
#define ED 128
#define NB 1024
#define NIX 780
#define XROW (NF * ED)      // 5120
#define KROW (NIX * ED)     // 99840
#define XB_BYTES (NB * NF * ED * 2)   // 13,107,200
#define KB_BYTES (NIX * ED * ED * 2)  // 25,559,040
#define WS_NEED (XB_BYTES + KB_BYTES)

typedef __attribute__((ext_vector_type(8))) short bf16x8;
typedef __attribute__((ext_vector_type(4))) float f32x4;
typedef __attribute__((ext_vector_type(4))) unsigned short ushx4;
typedef __attribute__((ext_vector_type(8))) unsigned short ushx8;

__device__ __forceinline__ unsigned short f2bf(float x) {
  unsigned int u = __float_as_uint(x);
  u = (u + 0x7FFFu + ((u >> 16) & 1u)) >> 16;
  return (unsigned short)u;
}
__device__ __forceinline__ float bf2f(unsigned short h) {
  return __uint_as_float(((unsigned int)h) << 16);
}

#define GLOAD16(gsrc, ldst)                                                    \
  __builtin_amdgcn_global_load_lds(                                            \
      (const __attribute__((address_space(1))) void*)(gsrc),                   \
      (__attribute__((address_space(3))) void*)(ldst), 16, 0, 0)

// ---- fused prepass: x fp32->bf16 (blocks 0..2559), K [e][n][d]->[n][e][d] bf16 ----
__global__ void cvt_fused(const float* __restrict__ x, const float* __restrict__ kr,
                          unsigned short* __restrict__ xb, unsigned short* __restrict__ kb) {
  const int blk = blockIdx.x;
  if (blk < 2560) {
    const size_t g = ((size_t)blk * 256 + threadIdx.x) * 8;
    float4 a = *reinterpret_cast<const float4*>(x + g);
    float4 b = *reinterpret_cast<const float4*>(x + g + 4);
    ushx8 h;
    h[0] = f2bf(a.x); h[1] = f2bf(a.y); h[2] = f2bf(a.z); h[3] = f2bf(a.w);
    h[4] = f2bf(b.x); h[5] = f2bf(b.y); h[6] = f2bf(b.z); h[7] = f2bf(b.w);
    *reinterpret_cast<ushx8*>(xb + g) = h;
  } else {
    const size_t g = ((size_t)(blk - 2560) * 256 + threadIdx.x) * 4;
    const int d = (int)(g & 127);
    const size_t t = g >> 7;
    const int e = (int)(t & 127);
    const int n = (int)(t >> 7);
    float4 v = *reinterpret_cast<const float4*>(kr + ((size_t)e * NIX + n) * ED + d);
    ushx4 h;
    h[0] = f2bf(v.x); h[1] = f2bf(v.y); h[2] = f2bf(v.z); h[3] = f2bf(v.w);
    *reinterpret_cast<ushx4*>(kb + g) = h;
  }
}

// ---- main kernel: e-split warps, 32-row b-tiles, XCD-locked b-range,
// ---- tile-PHASE ROTATION to de-correlate same-line L2 traffic across blocks.
__launch_bounds__(256, 4)
__global__ void opn_ws(const unsigned short* __restrict__ xb,
                       const unsigned short* __restrict__ kb,
                       float* __restrict__ out) {
  // 32 KB: K staging first; after hoist reused as P[0..4095] + Q[4096..8191]
  __shared__ unsigned short S[16384];
  __shared__ float scratch[4][32];   // per-warp partial dots

  const int bid = blockIdx.x;
  const int g8 = bid & 7;
  const int n = ((bid >> 3) << 1) + (g8 & 1);   // pair index, 0..779
  const int b0base = (g8 >> 1) * 256;           // b-slice locked to XCD pair
  const int phase = (bid >> 3) & 7;             // de-correlate tile sweep order

  const int tid = threadIdx.x;
  const int lane = tid & 63;
  const int w = tid >> 6;
  const int lm = lane & 15;
  const int lq = lane >> 4;
  const int col8 = lm * 8;

  // pair (fi, fj)
  int fi = 0, base = 0;
  while (base + (NF - 1 - fi) <= n) { base += NF - 1 - fi; ++fi; }
  const int fj = fi + 1 + (n - base);

  // ---- stage K (32 KB) via global_load_lds, pre-swizzled source ----
  {
    const unsigned short* ks = kb + (size_t)n * (ED * ED);
    #pragma unroll
    for (int j = 0; j < 8; ++j) {
      const int chunk = j * 4 + w;           // 0..31, 1KB each
      const int r = chunk * 4 + lq;          // 0..127
      const int c = col8 ^ ((r & 7) << 3);
      GLOAD16(ks + r * ED + c, S + chunk * 512);
    }
  }
  __syncthreads();

  // ---- hoist this warp's e-quarter: A[m=e][k=d], e = w*32 + f*16 + lm ----
  bf16x8 afr[4][2];
  #pragma unroll
  for (int kk = 0; kk < 4; ++kk)
    #pragma unroll
    for (int f = 0; f < 2; ++f) {
      const int r = w * 32 + f * 16 + lm;
      afr[kk][f] = *reinterpret_cast<const bf16x8*>(
          &S[r * ED + ((kk * 32 + lq * 8) ^ ((r & 7) << 3))]);
    }
  #pragma unroll
  for (int kk = 0; kk < 4; ++kk)
    #pragma unroll
    for (int f = 0; f < 2; ++f)
      asm volatile("" : "+v"(afr[kk][f]));   // pin: forbid remat from LDS
  __syncthreads();                            // all warps done reading K area

  unsigned short* Plds = S;                   // 8 KB
  unsigned short* Qlds = S + 4096;            // 8 KB

  #pragma unroll 1
  for (int t = 0; t < 8; ++t) {
    const int tt = (t + phase) & 7;           // rotated tile order
    const int b0 = b0base + tt * 32;

    // ---- stage P,Q (4 loads/thread, 16 KB) ----
    #pragma unroll
    for (int j = 0; j < 2; ++j) {
      const int chunk = j * 4 + w;           // 0..7
      const int r = chunk * 4 + lq;          // 0..31
      const int c = col8 ^ ((r & 7) << 3);
      const size_t xoff = (size_t)(b0 + r) * XROW + c;
      GLOAD16(xb + xoff + (size_t)fi * ED, Plds + chunk * 512);
      GLOAD16(xb + xoff + (size_t)fj * ED, Qlds + chunk * 512);
    }
    __syncthreads();   // full drain: tile staged

    // ---- T-quarter = K_w @ P^T : D[m=e][col=b], nt = b-subtile ----
    f32x4 acc[2][2];
    #pragma unroll
    for (int f = 0; f < 2; ++f)
      #pragma unroll
      for (int nt = 0; nt < 2; ++nt)
        acc[f][nt] = (f32x4){0.f, 0.f, 0.f, 0.f};

    __builtin_amdgcn_s_setprio(1);
    #pragma unroll
    for (int kk = 0; kk < 4; ++kk) {
      #pragma unroll
      for (int nt = 0; nt < 2; ++nt) {
        const int pb = nt * 16 + lm;
        bf16x8 pfr = *reinterpret_cast<const bf16x8*>(
            &Plds[pb * ED + ((kk * 32 + lq * 8) ^ ((pb & 7) << 3))]);
        #pragma unroll
        for (int f = 0; f < 2; ++f)
          acc[f][nt] = __builtin_amdgcn_mfma_f32_16x16x32_bf16(afr[kk][f], pfr, acc[f][nt], 0, 0, 0);
      }
    }
    __builtin_amdgcn_s_setprio(0);

    // ---- partial dot over this warp's e-quarter ----
    // lane holds T[e = w*32 + f*16 + lq*4 + r][b = nt*16 + lm]
    float s[2];
    #pragma unroll
    for (int nt = 0; nt < 2; ++nt) {
      const int qrow = nt * 16 + lm;
      float t0 = 0.f, t1 = 0.f, t2 = 0.f, t3 = 0.f;
      #pragma unroll
      for (int f = 0; f < 2; ++f) {
        const int c = (w * 32 + f * 16 + lq * 4) ^ ((qrow & 7) << 3);
        ushx4 q4 = *reinterpret_cast<const ushx4*>(&Qlds[qrow * ED + c]);
        t0 = fmaf(acc[f][nt][0], bf2f(q4[0]), t0);
        t1 = fmaf(acc[f][nt][1], bf2f(q4[1]), t1);
        t2 = fmaf(acc[f][nt][2], bf2f(q4[2]), t2);
        t3 = fmaf(acc[f][nt][3], bf2f(q4[3]), t3);
      }
      float sv = (t0 + t1) + (t2 + t3);
      sv += __shfl_xor(sv, 16);   // sum over lq groups (e-sub-quarters)
      sv += __shfl_xor(sv, 32);
      s[nt] = sv;
    }
    if (lq == 0) {                // lanes 0..15 of each warp
      scratch[w][lm] = s[0];
      scratch[w][16 + lm] = s[1];
    }
    __syncthreads();              // scratch ready; all tile reads done

    if (tid < 32) {               // cross-warp reduce + store
      const int b = tid;
      float r = (scratch[0][b] + scratch[1][b]) + (scratch[2][b] + scratch[3][b]);
      out[(size_t)(b0 + b) * NIX + n] = r;
    }
    // next stage writes Plds/Qlds, whose reads completed before the barrier;
    // the next scratch write is separated from this read by the next barrier.
  }
}

// ---------------- fallback (proven Round-1 kernel, used when ws too small) ----------------
__device__ __forceinline__ int swz_fb(int row, int col) {
  return row * 128 + (col ^ ((row & 7) << 3));
}

__launch_bounds__(256, 2)
__global__ void opn_fb(const float* __restrict__ x,
                       const float* __restrict__ kern,
                       float* __restrict__ out) {
  __shared__ unsigned short Klds[128 * 128];
  __shared__ unsigned short Plds[64 * 128];
  __shared__ unsigned short Qlds[64 * 132];

  const int n = blockIdx.x;
  const int tid = threadIdx.x;
  const int lane = tid & 63;
  const int w = tid >> 6;
  const int lm = lane & 15;
  const int lq = lane >> 4;

  int fi = 0, base = 0;
  while (base + (NF - 1 - fi) <= n) { base += NF - 1 - fi; ++fi; }
  const int fj = fi + 1 + (n - base);

  {
    const int r8 = tid >> 5;
    const int d0 = (tid & 31) * 4;
    const float* kbp = kern + (size_t)n * ED + d0;
    #pragma unroll
    for (int p = 0; p < 16; ++p) {
      int e = p * 8 + r8;
      float4 v = *reinterpret_cast<const float4*>(kbp + (size_t)e * KROW);
      ushx4 h;
      h[0] = f2bf(v.x); h[1] = f2bf(v.y); h[2] = f2bf(v.z); h[3] = f2bf(v.w);
      *reinterpret_cast<ushx4*>(&Klds[swz_fb(e, d0)]) = h;
    }
  }
  __syncthreads();

  bf16x8 bfr[4][8];
  #pragma unroll
  for (int kk = 0; kk < 4; ++kk)
    #pragma unroll
    for (int f = 0; f < 8; ++f)
      bfr[kk][f] = *reinterpret_cast<const bf16x8*>(
          &Klds[swz_fb(f * 16 + lm, kk * 32 + lq * 8)]);

  const int r8 = tid >> 5;
  const int c4 = (tid & 31) * 4;

  for (int t = 0; t < 8; ++t) {
    const int b0 = blockIdx.y * 512 + t * 64;
    __syncthreads();
    #pragma unroll
    for (int p = 0; p < 8; ++p) {
      int r = p * 8 + r8;
      const float* xbp = x + (size_t)(b0 + r) * XROW + c4;
      float4 vp = *reinterpret_cast<const float4*>(xbp + fi * ED);
      ushx4 hp;
      hp[0] = f2bf(vp.x); hp[1] = f2bf(vp.y); hp[2] = f2bf(vp.z); hp[3] = f2bf(vp.w);
      *reinterpret_cast<ushx4*>(&Plds[swz_fb(r, c4)]) = hp;
      float4 vq = *reinterpret_cast<const float4*>(xbp + fj * ED);
      ushx4 hq;
      hq[0] = f2bf(vq.x); hq[1] = f2bf(vq.y); hq[2] = f2bf(vq.z); hq[3] = f2bf(vq.w);
      *reinterpret_cast<ushx4*>(&Qlds[r * 132 + c4]) = hq;
    }
    __syncthreads();

    f32x4 acc[8];
    #pragma unroll
    for (int f = 0; f < 8; ++f) acc[f] = (f32x4){0.f, 0.f, 0.f, 0.f};
    #pragma unroll
    for (int kk = 0; kk < 4; ++kk) {
      bf16x8 a = *reinterpret_cast<const bf16x8*>(
          &Plds[swz_fb(w * 16 + lm, kk * 32 + lq * 8)]);
      #pragma unroll
      for (int f = 0; f < 8; ++f)
        acc[f] = __builtin_amdgcn_mfma_f32_16x16x32_bf16(a, bfr[kk][f], acc[f], 0, 0, 0);
    }

    #pragma unroll
    for (int r = 0; r < 4; ++r) {
      const int bl = w * 16 + lq * 4 + r;
      float s = 0.f;
      #pragma unroll
      for (int f = 0; f < 8; ++f)
        s = fmaf(acc[f][r], bf2f(Qlds[bl * 132 + f * 16 + lm]), s);
      s += __shfl_xor(s, 1);
      s += __shfl_xor(s, 2);
      s += __shfl_xor(s, 4);
      s += __shfl_xor(s, 8);
      if (lm == 0) out[(size_t)(b0 + bl) * NIX + n] = s;
    }
  }
}

extern "C" void kernel_launch(void* const* d_in, const int* in_sizes, int n_in,
                              void* d_out, int out_size, void* d_ws, size_t ws_size,
                              hipStream_t stream) {
  const float* x = (const float*)d_in[0];
  const float* kern = (const float*)d_in[1];
  float* out = (float*)d_out;
  (void)in_sizes; (void)n_in; (void)out_size;

  if (ws_size >= (size_t)WS_NEED) {
    unsigned short* xb = (unsigned short*)d_ws;
    unsigned short* kbuf = (unsigned short*)((char*)d_ws + XB_BYTES);
    cvt_fused<<<15040, 256, 0, stream>>>(x, kern, xb, kbuf);
    opn_ws<<<3120, 256, 0, stream>>>(xb, kbuf, out);  // 390*8: bid%8 locks b-slice to XCD
  } else {
    dim3 grid(NIX, 2, 1);
    opn_fb<<<grid, 256, 0, stream>>>(x, kern, out);
  }
}